// Round 1
// baseline (780.105 us; speedup 1.0000x reference)
//
#include <hip/hip_runtime.h>

typedef short short8 __attribute__((ext_vector_type(8)));
typedef float f32x4 __attribute__((ext_vector_type(4)));

#define XP_BYTES (16ull * 130 * 130 * 128 * 2)

static __device__ __forceinline__ unsigned short f2bf(float f) {
  unsigned u = __float_as_uint(f);
  u += 0x7FFFu + ((u >> 16) & 1u);
  return (unsigned short)(u >> 16);
}

static __device__ __forceinline__ void gload16(const void* g, void* l) {
  __builtin_amdgcn_global_load_lds(
      (const __attribute__((address_space(1))) void*)g,
      (__attribute__((address_space(3))) void*)l, 16, 0, 0);
}

// ---------------- weight rotation: (O*R,I,3,3) fp32 -> W2[n'=o*8+r][tap*128+ic] bf16
static __device__ __forceinline__ float wtap(const float* f, int yi, int xi) {
  bool valid = (yi >= 0) & (yi < 3) & (xi >= 0) & (xi < 3);
  int yc = min(max(yi, 0), 2), xc = min(max(xi, 0), 2);
  return valid ? f[yc * 3 + xc] : 0.f;
}

__global__ __launch_bounds__(256) void wprep_kernel(
    const float* __restrict__ w, const float* __restrict__ rot_alpha,
    unsigned short* __restrict__ w2) {
  int gid = blockIdx.x * 256 + threadIdx.x;  // 131072 = 1024 * 128
  int ic = gid & 127;
  int nr = gid >> 7;  // n' = o*8 + r  (matches weight channel o*8+r)
  int r = nr & 7;
  const float* wf = w + (size_t)nr * (128 * 9) + (size_t)ic * 9;
  float f[9];
#pragma unroll
  for (int q = 0; q < 9; ++q) f[q] = wf[q];
  float ang = rot_alpha[r] * 0.78539816339744830962f * (float)r;
  float sth, cth;
  sincosf(ang, &sth, &cth);
#pragma unroll
  for (int j = 0; j < 3; ++j) {
#pragma unroll
    for (int i = 0; i < 3; ++i) {
      float gy = (float)(j - 1), gx = (float)(i - 1);
      float xs = cth * gx - sth * gy;
      float ys = sth * gx + cth * gy;
      float ix = xs + 1.0f, iy = ys + 1.0f;  // (v+1)*0.5*(k-1), k=3
      float x0f = floorf(ix), y0f = floorf(iy);
      int x0 = (int)x0f, y0 = (int)y0f;
      float wx = ix - x0f, wy = iy - y0f;
      float acc = wtap(f, y0, x0) * (1.f - wy) * (1.f - wx)
                + wtap(f, y0, x0 + 1) * (1.f - wy) * wx
                + wtap(f, y0 + 1, x0) * wy * (1.f - wx)
                + wtap(f, y0 + 1, x0 + 1) * wy * wx;
      w2[(size_t)nr * 1152 + (size_t)(j * 3 + i) * 128 + ic] = f2bf(acc);
    }
  }
}

// ---------------- x: NCHW fp32 -> padded NHWC bf16 xp[16][130][130][128]
__global__ __launch_bounds__(256) void xprep_kernel(
    const float* __restrict__ x, unsigned short* __restrict__ xp) {
  const int yy = blockIdx.x;  // 0..129
  const int b = blockIdx.y;   // 0..15
  const int t = threadIdx.x;
  const size_t rowbase = ((size_t)b * 130 + yy) * (130 * 128);  // elements
  if (yy == 0 || yy == 129) {
    uint4 z = {0u, 0u, 0u, 0u};
    for (int i = t; i < 2080; i += 256)  // 130*128*2B / 16B
      ((uint4*)(xp + rowbase))[i] = z;
    return;
  }
  const int y = yy - 1;
  __shared__ float lt[32][129];
  if (t < 32) {  // zero x-borders
    uint4 z = {0u, 0u, 0u, 0u};
    int xx = (t < 16) ? 0 : 129;
    int cc = (t & 15) * 8;
    *(uint4*)(xp + rowbase + (size_t)xx * 128 + cc) = z;
  }
  for (int c0 = 0; c0 < 128; c0 += 32) {
#pragma unroll
    for (int i = 0; i < 16; ++i) {
      int idx = i * 256 + t;
      int c = idx >> 7, wq = idx & 127;
      lt[c][wq] = x[(((size_t)b * 128 + c0 + c) * 128 + y) * 128 + wq];
    }
    __syncthreads();
#pragma unroll
    for (int i = 0; i < 2; ++i) {
      int u = i * 256 + t;
      int xx = u >> 2, cp = (u & 3) * 8;
      unsigned short v[8];
#pragma unroll
      for (int q = 0; q < 8; ++q) v[q] = f2bf(lt[cp + q][xx]);
      *(uint4*)(xp + rowbase + (size_t)(xx + 1) * 128 + c0 + cp) = *(uint4*)v;
    }
    __syncthreads();
  }
}

// ---------------- implicit-GEMM conv + fused max over 8 rotations
// Block: 256 thr (4 waves), tile 128 pixels (one image row) x 128 n'.
// K = 9 taps * 128 ch, BK = 32. A: xp[b][y+dy][x+dx][c], B: w2[n'][tap*128+c].
__global__ __launch_bounds__(256, 3) void conv_kernel(
    const unsigned short* __restrict__ xp,
    const unsigned short* __restrict__ w2,
    float* __restrict__ out) {
  __shared__ unsigned short lA[128 * 32];  // [pix][32c]  8 KiB
  __shared__ unsigned short lB[128 * 32];  // [n'][32k]   8 KiB
  __shared__ float lE[128 * 17];           // epilogue    8.5 KiB

  const int tid = threadIdx.x;
  const int lane = tid & 63;
  const int wv = tid >> 6;
  const int wr = wv >> 1;  // wave row block (pixels)
  const int wc = wv & 1;   // wave col block (n')

  const int nb = blockIdx.x;  // 0..7  -> n' in [nb*128, nb*128+128)
  const int by = blockIdx.y;  // 0..2047
  const int b = by >> 7;
  const int y = by & 127;

  f32x4 acc[4][4];
#pragma unroll
  for (int m = 0; m < 4; ++m)
#pragma unroll
    for (int n = 0; n < 4; ++n) acc[m][n] = (f32x4){0.f, 0.f, 0.f, 0.f};

  const int pixA = tid >> 2;        // chunk decode (same for A-pixel / B-n')
  const int cpA = (tid & 3) << 3;   // 8-element sub-offset

  char* ldsAw = (char*)lA + wv * 1024;
  char* ldsBw = (char*)lB + wv * 1024;

  const size_t xrow0 = ((size_t)(b * 130 + y) * 130) * 128;
  const size_t bcol0 = (size_t)nb * 128 * 1152;

  for (int tap = 0; tap < 9; ++tap) {
    const int dy = tap / 3;
    const int dx = tap - dy * 3;
    const size_t abase = xrow0 + (size_t)dy * (130 * 128) + (size_t)dx * 128;
    const size_t bbase = bcol0 + (size_t)tap * 128;
#pragma unroll
    for (int cb = 0; cb < 4; ++cb) {
      const unsigned short* ga = xp + abase + cb * 32 + (size_t)pixA * 128 + cpA;
      const unsigned short* gb = w2 + bbase + cb * 32 + (size_t)pixA * 1152 + cpA;
      gload16(ga, ldsAw);
      gload16(ga + 64 * 128, ldsAw + 4096);
      gload16(gb, ldsBw);
      gload16(gb + 64 * 1152, ldsBw + 4096);
      __syncthreads();  // drains vmcnt before barrier
      short8 af[4], bf[4];
      const int lrow = lane & 15;
      const int koff = (lane >> 4) << 3;
#pragma unroll
      for (int m = 0; m < 4; ++m)
        af[m] = *(const short8*)(lA + ((wr * 64 + m * 16 + lrow) * 32 + koff));
#pragma unroll
      for (int n = 0; n < 4; ++n)
        bf[n] = *(const short8*)(lB + ((wc * 64 + n * 16 + lrow) * 32 + koff));
#pragma unroll
      for (int m = 0; m < 4; ++m)
#pragma unroll
        for (int n = 0; n < 4; ++n)
          acc[m][n] = __builtin_amdgcn_mfma_f32_16x16x32_bf16(af[m], bf[n],
                                                              acc[m][n], 0, 0, 0);
      __syncthreads();
    }
  }

  // max over 8 rotations = 8 adjacent n' columns (cols live in lane&15)
#pragma unroll
  for (int m = 0; m < 4; ++m)
#pragma unroll
    for (int n = 0; n < 4; ++n)
#pragma unroll
      for (int j = 0; j < 4; ++j) {
        float v = acc[m][n][j];
        v = fmaxf(v, __shfl_xor(v, 1, 64));
        v = fmaxf(v, __shfl_xor(v, 2, 64));
        v = fmaxf(v, __shfl_xor(v, 4, 64));
        if ((lane & 7) == 0) {
          int xx = wr * 64 + m * 16 + ((lane >> 4) << 2) + j;  // pixel
          int ol = (wc * 64 + n * 16 + (lane & 15)) >> 3;      // o_local 0..15
          lE[xx * 17 + ol] = v;
        }
      }
  __syncthreads();
  const size_t obase = (((size_t)b * 128 + nb * 16) * 128 + y) * 128;
#pragma unroll
  for (int i = 0; i < 8; ++i) {
    int idx = i * 256 + tid;
    int ol = idx >> 7;
    int xx = idx & 127;
    out[obase + (size_t)ol * (128 * 128) + xx] = lE[xx * 17 + ol];
  }
}

extern "C" void kernel_launch(void* const* d_in, const int* in_sizes, int n_in,
                              void* d_out, int out_size, void* d_ws, size_t ws_size,
                              hipStream_t stream) {
  const float* x = (const float*)d_in[0];
  const float* w = (const float*)d_in[1];
  const float* ra = (const float*)d_in[2];
  float* out = (float*)d_out;
  unsigned short* xp = (unsigned short*)d_ws;                      // 69,222,400 B
  unsigned short* w2 = (unsigned short*)((char*)d_ws + XP_BYTES);  // 2,359,296 B

  hipLaunchKernelGGL(wprep_kernel, dim3(512), dim3(256), 0, stream, w, ra, w2);
  hipLaunchKernelGGL(xprep_kernel, dim3(130, 16), dim3(256), 0, stream, x, xp);
  hipLaunchKernelGGL(conv_kernel, dim3(8, 2048), dim3(256), 0, stream, xp, w2, out);
}

// Round 2
// 756.213 us; speedup vs baseline: 1.0316x; 1.0316x over previous
//
#include <hip/hip_runtime.h>

typedef short short8 __attribute__((ext_vector_type(8)));
typedef float f32x4 __attribute__((ext_vector_type(4)));

#define XP_BYTES (16ull * 130 * 130 * 128 * 2)

static __device__ __forceinline__ unsigned short f2bf(float f) {
  unsigned u = __float_as_uint(f);
  u += 0x7FFFu + ((u >> 16) & 1u);
  return (unsigned short)(u >> 16);
}

static __device__ __forceinline__ void gload16(const void* g, void* l) {
  __builtin_amdgcn_global_load_lds(
      (const __attribute__((address_space(1))) void*)g,
      (__attribute__((address_space(3))) void*)l, 16, 0, 0);
}

// ---------------- weight rotation: (O*R,I,3,3) fp32 -> W2[n'=o*8+r][tap*128+ic] bf16
static __device__ __forceinline__ float wtap(const float* f, int yi, int xi) {
  bool valid = (yi >= 0) & (yi < 3) & (xi >= 0) & (xi < 3);
  int yc = min(max(yi, 0), 2), xc = min(max(xi, 0), 2);
  return valid ? f[yc * 3 + xc] : 0.f;
}

__global__ __launch_bounds__(256) void wprep_kernel(
    const float* __restrict__ w, const float* __restrict__ rot_alpha,
    unsigned short* __restrict__ w2) {
  int gid = blockIdx.x * 256 + threadIdx.x;  // 131072 = 1024 * 128
  int ic = gid & 127;
  int nr = gid >> 7;  // n' = o*8 + r
  int r = nr & 7;
  const float* wf = w + (size_t)nr * (128 * 9) + (size_t)ic * 9;
  float f[9];
#pragma unroll
  for (int q = 0; q < 9; ++q) f[q] = wf[q];
  float ang = rot_alpha[r] * 0.78539816339744830962f * (float)r;
  float sth, cth;
  sincosf(ang, &sth, &cth);
#pragma unroll
  for (int j = 0; j < 3; ++j) {
#pragma unroll
    for (int i = 0; i < 3; ++i) {
      float gy = (float)(j - 1), gx = (float)(i - 1);
      float xs = cth * gx - sth * gy;
      float ys = sth * gx + cth * gy;
      float ix = xs + 1.0f, iy = ys + 1.0f;
      float x0f = floorf(ix), y0f = floorf(iy);
      int x0 = (int)x0f, y0 = (int)y0f;
      float wx = ix - x0f, wy = iy - y0f;
      float acc = wtap(f, y0, x0) * (1.f - wy) * (1.f - wx)
                + wtap(f, y0, x0 + 1) * (1.f - wy) * wx
                + wtap(f, y0 + 1, x0) * wy * (1.f - wx)
                + wtap(f, y0 + 1, x0 + 1) * wy * wx;
      w2[(size_t)nr * 1152 + (size_t)(j * 3 + i) * 128 + ic] = f2bf(acc);
    }
  }
}

// ---------------- x: NCHW fp32 -> padded NHWC bf16 xp[16][130][130][128]
__global__ __launch_bounds__(256) void xprep_kernel(
    const float* __restrict__ x, unsigned short* __restrict__ xp) {
  const int yy = blockIdx.x;  // 0..129
  const int b = blockIdx.y;   // 0..15
  const int t = threadIdx.x;
  const size_t rowbase = ((size_t)b * 130 + yy) * (130 * 128);
  if (yy == 0 || yy == 129) {
    uint4 z = {0u, 0u, 0u, 0u};
    for (int i = t; i < 2080; i += 256)
      ((uint4*)(xp + rowbase))[i] = z;
    return;
  }
  const int y = yy - 1;
  __shared__ float lt[32][129];
  if (t < 32) {
    uint4 z = {0u, 0u, 0u, 0u};
    int xx = (t < 16) ? 0 : 129;
    int cc = (t & 15) * 8;
    *(uint4*)(xp + rowbase + (size_t)xx * 128 + cc) = z;
  }
  for (int c0 = 0; c0 < 128; c0 += 32) {
#pragma unroll
    for (int i = 0; i < 16; ++i) {
      int idx = i * 256 + t;
      int c = idx >> 7, wq = idx & 127;
      lt[c][wq] = x[(((size_t)b * 128 + c0 + c) * 128 + y) * 128 + wq];
    }
    __syncthreads();
#pragma unroll
    for (int i = 0; i < 2; ++i) {
      int u = i * 256 + t;
      int xx = u >> 2, cp = (u & 3) * 8;
      unsigned short v[8];
#pragma unroll
      for (int q = 0; q < 8; ++q) v[q] = f2bf(lt[cp + q][xx]);
      *(uint4*)(xp + rowbase + (size_t)(xx + 1) * 128 + c0 + cp) = *(uint4*)v;
    }
    __syncthreads();
  }
}

// ---------------- implicit-GEMM conv, 256x256 tile, BK=64, 8 waves, counted-vmcnt pipeline
// M = pixel (b,y,x), N = n' = o*8+r, K = tap*128 + c (1152). Fused max over 8 rotations.
// LDS: A[2buf][2half][128 rows][64ch] + B same = 128 KiB. Swizzle slot^=(row&7) both sides.
__global__ __launch_bounds__(512, 2) void conv_kernel(
    const unsigned short* __restrict__ xp,
    const unsigned short* __restrict__ w2,
    float* __restrict__ out) {
  __shared__ unsigned short lds[65536];  // 128 KiB

  const int tid = threadIdx.x;
  const int lane = tid & 63;
  const int wv = tid >> 6;  // 0..7
  const int wr = wv >> 2;   // M half (0..1): rows wr*128..+128
  const int wc = wv & 3;    // N quarter (0..3): cols wc*64..+64

  // XCD-aware swizzle (4096 blocks % 8 == 0); consecutive wg share the A-tile
  const int bid = blockIdx.x;
  const int wg = (bid & 7) * 512 + (bid >> 3);
  const int mblk = wg >> 2;  // 0..1023
  const int nblk = wg & 3;   // 0..3
  const int b = mblk >> 6;
  const int y0 = (mblk & 63) << 1;  // block covers image rows y0, y0+1

  const int r0 = tid >> 3;  // staging row (chunk>>3), +64 for i=1
  const int s0 = tid & 7;   // staging LDS slot
  const int wvoff = wv * 512;  // shorts: per-wave LDS chunk base

  const unsigned short* xbase = xp + (size_t)(b * 130 + y0) * 130 * 128;
  const unsigned short* wbase = w2 + (size_t)nblk * 256 * 1152;

  const int l15 = lane & 15;
  const int lhi = lane >> 4;
  const int swz = lhi ^ (l15 & 7);  // read slot for kk=0; kk=1 -> swz^4

  f32x4 acc[8][4];
#pragma unroll
  for (int mf = 0; mf < 8; ++mf)
#pragma unroll
    for (int nf = 0; nf < 4; ++nf) acc[mf][nf] = (f32x4){0.f, 0.f, 0.f, 0.f};

  auto stage = [&](int pb, int kt) {
    const int tap = kt >> 1;
    const int dy = tap / 3;
    const int dx = tap - dy * 3;
    const int c0 = (kt & 1) << 6;
    unsigned short* la = lds + pb * 16384;
    unsigned short* lb = lds + 32768 + pb * 16384;
#pragma unroll
    for (int hp = 0; hp < 2; ++hp)
#pragma unroll
      for (int i = 0; i < 2; ++i) {
        int r = i * 64 + r0;               // pixel x within tile-half
        int gs = s0 ^ (r & 7);             // inverse swizzle on global source
        const unsigned short* ga =
            xbase + ((size_t)((hp + dy) * 130) + r + dx) * 128 + c0 + gs * 8;
        gload16(ga, la + hp * 8192 + i * 4096 + wvoff);
      }
#pragma unroll
    for (int hn = 0; hn < 2; ++hn)
#pragma unroll
      for (int i = 0; i < 2; ++i) {
        int r = i * 64 + r0;               // n' within tile-half
        int gs = s0 ^ (r & 7);
        const unsigned short* gb =
            wbase + (size_t)(hn * 128 + r) * 1152 + tap * 128 + c0 + gs * 8;
        gload16(gb, lb + hn * 8192 + i * 4096 + wvoff);
      }
  };

  stage(0, 0);

#pragma unroll 2
  for (int kt = 0; kt < 18; ++kt) {
    const int pb = kt & 1;
    if (kt < 17) {
      stage(pb ^ 1, kt + 1);                          // prefetch next K-tile
      asm volatile("s_waitcnt vmcnt(8)" ::: "memory");  // wait ONLY current tile
    } else {
      asm volatile("s_waitcnt vmcnt(0)" ::: "memory");
    }
    __builtin_amdgcn_s_barrier();

    const unsigned short* pA = lds + pb * 16384 + wr * 8192 + l15 * 64;
    const unsigned short* pB =
        lds + 32768 + pb * 16384 + (wc >> 1) * 8192 + (wc & 1) * 4096 + l15 * 64;
#pragma unroll
    for (int kk = 0; kk < 2; ++kk) {
      const int sl = (swz ^ (kk << 2)) * 8;
      short8 bf[4];
#pragma unroll
      for (int nf = 0; nf < 4; ++nf)
        bf[nf] = *(const short8*)(pB + nf * 1024 + sl);
#pragma unroll
      for (int mh = 0; mh < 2; ++mh) {
        short8 af[4];
#pragma unroll
        for (int q = 0; q < 4; ++q)
          af[q] = *(const short8*)(pA + (mh * 4 + q) * 1024 + sl);
        __builtin_amdgcn_s_setprio(1);
#pragma unroll
        for (int q = 0; q < 4; ++q)
#pragma unroll
          for (int nf = 0; nf < 4; ++nf)
            acc[mh * 4 + q][nf] = __builtin_amdgcn_mfma_f32_16x16x32_bf16(
                af[q], bf[nf], acc[mh * 4 + q][nf], 0, 0, 0);
        __builtin_amdgcn_s_setprio(0);
      }
    }
    __builtin_amdgcn_s_barrier();
  }

  // ---- epilogue: max over 8 rotations (8 adjacent n' cols), then coalesced store
  float* lE = (float*)lds;  // [256 pix][33] fp32, reuses GEMM LDS
#pragma unroll
  for (int mf = 0; mf < 8; ++mf)
#pragma unroll
    for (int nf = 0; nf < 4; ++nf)
#pragma unroll
      for (int j = 0; j < 4; ++j) {
        float v = acc[mf][nf][j];
        v = fmaxf(v, __shfl_xor(v, 1, 64));
        v = fmaxf(v, __shfl_xor(v, 2, 64));
        v = fmaxf(v, __shfl_xor(v, 4, 64));
        if ((lane & 7) == 0) {
          int pix = wr * 128 + mf * 16 + lhi * 4 + j;
          int ol = wc * 8 + nf * 2 + ((lane >> 3) & 1);
          lE[pix * 33 + ol] = v;
        }
      }
  __syncthreads();
  const size_t obase = ((size_t)(b * 128 + nblk * 32) * 128 + y0) * 128;
#pragma unroll
  for (int i = 0; i < 16; ++i) {
    int idx = i * 512 + tid;
    int ol = idx >> 8;   // 0..31
    int pix = idx & 255;
    int yl = pix >> 7;
    int xx = pix & 127;
    out[obase + (size_t)ol * 16384 + yl * 128 + xx] = lE[pix * 33 + ol];
  }
}

extern "C" void kernel_launch(void* const* d_in, const int* in_sizes, int n_in,
                              void* d_out, int out_size, void* d_ws, size_t ws_size,
                              hipStream_t stream) {
  const float* x = (const float*)d_in[0];
  const float* w = (const float*)d_in[1];
  const float* ra = (const float*)d_in[2];
  float* out = (float*)d_out;
  unsigned short* xp = (unsigned short*)d_ws;
  unsigned short* w2 = (unsigned short*)((char*)d_ws + XP_BYTES);

  hipLaunchKernelGGL(wprep_kernel, dim3(512), dim3(256), 0, stream, w, ra, w2);
  hipLaunchKernelGGL(xprep_kernel, dim3(130, 16), dim3(256), 0, stream, x, xp);
  hipLaunchKernelGGL(conv_kernel, dim3(4096), dim3(512), 0, stream, xp, w2, out);
}